// Round 1
// baseline (1034.813 us; speedup 1.0000x reference)
//
#include <hip/hip_runtime.h>
#include <hip/hip_bf16.h>

#define T_TASKS 8
#define B_ROWS 4096
#define BM 128
#define BN 128
#define BK 32
#define LDSS 40           // LDS row stride in bf16 elems (80 B, 16B-aligned)
#define MAXTILES 40       // sum over tasks of ceil(cnt/BM) <= T + B/BM = 40

typedef __attribute__((ext_vector_type(4))) float f32x4;
typedef __attribute__((ext_vector_type(8))) short bf16x8;

__device__ __forceinline__ unsigned short f32_to_bf16(float f) {
    union { float f; unsigned int u; } v; v.f = f;
    unsigned int r = v.u + 0x7FFF + ((v.u >> 16) & 1);  // RNE
    return (unsigned short)(r >> 16);
}

// ---------------- setup: counting sort by task + tile table ----------------
__global__ void setup_kernel(const int* __restrict__ task, int* __restrict__ perm,
                             int* __restrict__ offs, int* __restrict__ table) {
    __shared__ int cnt[T_TASKS];
    __shared__ int cur[T_TASKS];
    int tid = threadIdx.x;
    if (tid < T_TASKS) cnt[tid] = 0;
    __syncthreads();
    for (int b = tid; b < B_ROWS; b += blockDim.x)
        atomicAdd(&cnt[task[b]], 1);
    __syncthreads();
    if (tid == 0) {
        int o = 0;
        for (int t = 0; t < T_TASKS; ++t) { offs[t] = o; cur[t] = o; o += cnt[t]; }
        offs[T_TASKS] = o;
        int s = 0;
        for (int t = 0; t < T_TASKS; ++t) {
            int nt = (cnt[t] + BM - 1) / BM;
            for (int j = 0; j < nt; ++j) table[s++] = (t << 16) | j;
        }
        for (; s < MAXTILES; ++s) table[s] = -1;
    }
    __syncthreads();
    for (int b = tid; b < B_ROWS; b += blockDim.x) {
        int t = task[b];
        int pos = atomicAdd(&cur[t], 1);
        perm[pos] = b;
    }
}

// ---------------- permute + cast x -> bf16 ----------------
__global__ void permute_cast_kernel(const float* __restrict__ x, const int* __restrict__ perm,
                                    unsigned short* __restrict__ xp) {
    int rowp = blockIdx.x;
    int src = perm[rowp];
    const float4* xin = reinterpret_cast<const float4*>(x + (size_t)src * 1024);
    unsigned short* dst = xp + (size_t)rowp * 1024;
    int c4 = threadIdx.x;   // 256 threads, 256 float4 per row
    float4 v = xin[c4];
    ushort4 o;
    o.x = f32_to_bf16(v.x); o.y = f32_to_bf16(v.y);
    o.z = f32_to_bf16(v.z); o.w = f32_to_bf16(v.w);
    *reinterpret_cast<ushort4*>(dst + c4 * 4) = o;
}

// ---------------- VAE reparameterization ----------------
__global__ void vae_kernel(const float* __restrict__ scat, const float* __restrict__ eps,
                           const int* __restrict__ perm, unsigned short* __restrict__ z) {
    int rowp = blockIdx.x;
    int c = threadIdx.x;            // 256
    int src = perm[rowp];
    float mu = scat[(size_t)rowp * 512 + c];
    float ls = scat[(size_t)rowp * 512 + 256 + c];
    float e  = eps[(size_t)src * 256 + c];
    z[(size_t)rowp * 256 + c] = f32_to_bf16(mu + __expf(ls) * e);
}

// ---------------- grouped GEMM: C = relu/sigmoid/none(A @ W[t] + b[t]) ----------------
// A: bf16 [rowp][K] (rows grouped by task). W: f32 [t][K][N]. bias: f32 [t][N].
// MODE 0: relu -> bf16 store (row-major, permuted space)
// MODE 1: plain f32 store (scat)
// MODE 2: sigmoid -> f32 scatter store to original row order via perm
template<int MODE>
__global__ __launch_bounds__(256, 2)
void gemm_kernel(const unsigned short* __restrict__ A, const float* __restrict__ W,
                 const float* __restrict__ bias, void* __restrict__ dst,
                 const int* __restrict__ offs, const int* __restrict__ table,
                 const int* __restrict__ perm,
                 int K, int N, int ldd, int Btot)
{
    int t, mtile, off, cnt;
    if (table != nullptr) {
        int v = table[blockIdx.x];
        if (v < 0) return;
        t = v >> 16; mtile = v & 0xFFFF;
        off = offs[t]; cnt = offs[t + 1] - off;
    } else {
        t = 0; mtile = blockIdx.x; off = 0; cnt = Btot;
    }
    const int n0 = blockIdx.y * BN;
    const float* Wt = W + (size_t)t * K * N;

    __shared__ unsigned short As[BM][LDSS];
    __shared__ unsigned short Bs[BN][LDSS];

    const int tid  = threadIdx.x;
    const int lane = tid & 63;
    const int wave = tid >> 6;
    const int wr = wave >> 1, wc = wave & 1;

    f32x4 acc[4][4];
    #pragma unroll
    for (int m = 0; m < 4; ++m)
        #pragma unroll
        for (int n = 0; n < 4; ++n)
            acc[m][n] = (f32x4){0.f, 0.f, 0.f, 0.f};

    for (int k0 = 0; k0 < K; k0 += BK) {
        // ---- stage A tile (bf16, 128x32), 16B per thread x2 ----
        #pragma unroll
        for (int it = 0; it < 2; ++it) {
            int c  = it * 256 + tid;        // 0..511
            int mm = c >> 2;                // 0..127
            int kk = (c & 3) << 3;          // 0,8,16,24
            int local = mtile * BM + mm;
            uint4 v = make_uint4(0u, 0u, 0u, 0u);
            if (local < cnt)
                v = *reinterpret_cast<const uint4*>(A + (size_t)(off + local) * K + k0 + kk);
            *reinterpret_cast<uint4*>(&As[mm][kk]) = v;
        }
        // ---- stage B tile transposed (f32 -> bf16), Bs[n][k] ----
        #pragma unroll
        for (int it = 0; it < 8; ++it) {
            int c  = it * 256 + tid;        // 0..2047
            int kk = c >> 6;                // 0..31
            int nn = (c & 63) << 1;         // 0..126 even
            const float2 v = *reinterpret_cast<const float2*>(
                Wt + (size_t)(k0 + kk) * N + n0 + nn);
            Bs[nn][kk]     = f32_to_bf16(v.x);
            Bs[nn + 1][kk] = f32_to_bf16(v.y);
        }
        __syncthreads();

        bf16x8 af[4], bfr[4];
        #pragma unroll
        for (int m = 0; m < 4; ++m)
            af[m] = *reinterpret_cast<const bf16x8*>(
                &As[wr * 64 + m * 16 + (lane & 15)][(lane >> 4) * 8]);
        #pragma unroll
        for (int n = 0; n < 4; ++n)
            bfr[n] = *reinterpret_cast<const bf16x8*>(
                &Bs[wc * 64 + n * 16 + (lane & 15)][(lane >> 4) * 8]);

        #pragma unroll
        for (int m = 0; m < 4; ++m)
            #pragma unroll
            for (int n = 0; n < 4; ++n)
                acc[m][n] = __builtin_amdgcn_mfma_f32_16x16x32_bf16(af[m], bfr[n], acc[m][n], 0, 0, 0);
        __syncthreads();
    }

    // ---- epilogue ----
    const float* bt = bias + (size_t)t * N;
    #pragma unroll
    for (int n = 0; n < 4; ++n) {
        int col = n0 + wc * 64 + n * 16 + (lane & 15);
        float bv = bt[col];
        #pragma unroll
        for (int m = 0; m < 4; ++m) {
            int rbase = mtile * BM + wr * 64 + m * 16 + ((lane >> 4) << 2);
            #pragma unroll
            for (int j = 0; j < 4; ++j) {
                int local = rbase + j;
                if (local >= cnt) continue;
                float v = acc[m][n][j] + bv;
                if (MODE == 0) {
                    ((unsigned short*)dst)[(size_t)(off + local) * ldd + col] =
                        f32_to_bf16(fmaxf(v, 0.f));
                } else if (MODE == 1) {
                    ((float*)dst)[(size_t)(off + local) * ldd + col] = v;
                } else {
                    int grow = perm[off + local];
                    ((float*)dst)[(size_t)grow * ldd + col] = 1.f / (1.f + __expf(-v));
                }
            }
        }
    }
}

extern "C" void kernel_launch(void* const* d_in, const int* in_sizes, int n_in,
                              void* d_out, int out_size, void* d_ws, size_t ws_size,
                              hipStream_t stream) {
    const float* x      = (const float*)d_in[0];
    const int*   task   = (const int*)d_in[1];
    const float* eps    = (const float*)d_in[2];
    const float* enc_W1 = (const float*)d_in[3];
    const float* enc_b1 = (const float*)d_in[4];
    const float* enc_W2 = (const float*)d_in[5];
    const float* enc_b2 = (const float*)d_in[6];
    const float* enc_W3 = (const float*)d_in[7];
    const float* enc_b3 = (const float*)d_in[8];
    const float* enc_W4 = (const float*)d_in[9];
    const float* enc_b4 = (const float*)d_in[10];
    const float* ds_W1  = (const float*)d_in[11];
    const float* ds_b1  = (const float*)d_in[12];
    const float* ds_W2  = (const float*)d_in[13];
    const float* ds_b2  = (const float*)d_in[14];
    const float* hd_W1  = (const float*)d_in[15];
    const float* hd_b1  = (const float*)d_in[16];
    const float* hd_W2  = (const float*)d_in[17];
    const float* hd_b2  = (const float*)d_in[18];
    float* out = (float*)d_out;

    char* ws = (char*)d_ws;
    int* perm  = (int*)ws;  ws += B_ROWS * 4;
    int* offs  = (int*)ws;  ws += 256;
    int* table = (int*)ws;  ws += 256;
    unsigned short* xp = (unsigned short*)ws; ws += (size_t)B_ROWS * 1024 * 2;
    unsigned short* h1 = (unsigned short*)ws; ws += (size_t)B_ROWS * 2048 * 2;
    unsigned short* h2 = (unsigned short*)ws; ws += (size_t)B_ROWS * 2048 * 2;
    unsigned short* zb = (unsigned short*)ws; ws += (size_t)B_ROWS * 256 * 2;
    float* scat = out;   // reuse d_out (16 MB) as 8 MB scat scratch; fully overwritten later

    setup_kernel<<<1, 1024, 0, stream>>>(task, perm, offs, table);
    permute_cast_kernel<<<B_ROWS, 256, 0, stream>>>(x, perm, xp);

    // encoder (grouped by task)
    gemm_kernel<0><<<dim3(MAXTILES, 16), 256, 0, stream>>>(xp, enc_W1, enc_b1, h1, offs, table, nullptr, 1024, 2048, 2048, B_ROWS);
    gemm_kernel<0><<<dim3(MAXTILES, 16), 256, 0, stream>>>(h1, enc_W2, enc_b2, h2, offs, table, nullptr, 2048, 2048, 2048, B_ROWS);
    gemm_kernel<0><<<dim3(MAXTILES, 16), 256, 0, stream>>>(h2, enc_W3, enc_b3, h1, offs, table, nullptr, 2048, 2048, 2048, B_ROWS);
    gemm_kernel<1><<<dim3(MAXTILES, 4), 256, 0, stream>>>(h1, enc_W4, enc_b4, scat, offs, table, nullptr, 2048, 512, 512, B_ROWS);

    vae_kernel<<<B_ROWS, 256, 0, stream>>>(scat, eps, perm, zb);

    // decoder shared layers (ungrouped: t=0, all rows)
    gemm_kernel<0><<<dim3(32, 16), 256, 0, stream>>>(zb, ds_W1, ds_b1, h2, nullptr, nullptr, nullptr, 256, 2048, 2048, B_ROWS);
    gemm_kernel<0><<<dim3(32, 16), 256, 0, stream>>>(h2, ds_W2, ds_b2, h1, nullptr, nullptr, nullptr, 2048, 2048, 2048, B_ROWS);

    // heads (grouped)
    gemm_kernel<0><<<dim3(MAXTILES, 16), 256, 0, stream>>>(h1, hd_W1, hd_b1, h2, offs, table, nullptr, 2048, 2048, 2048, B_ROWS);
    gemm_kernel<2><<<dim3(MAXTILES, 8), 256, 0, stream>>>(h2, hd_W2, hd_b2, out, offs, table, perm, 2048, 1024, 1024, B_ROWS);
}

// Round 2
// 702.200 us; speedup vs baseline: 1.4737x; 1.4737x over previous
//
#include <hip/hip_runtime.h>
#include <hip/hip_bf16.h>

#define T_TASKS 8
#define B_ROWS 4096
#define PADROWS 4224      // +128 so partial-tile global_load_lds overreads stay in-bounds
#define BM 128
#define BN 128
#define BK 32
#define LDSS 40           // round-1 fallback LDS stride
#define MAXTILES 40

typedef __attribute__((ext_vector_type(4))) float f32x4;
typedef __attribute__((ext_vector_type(8))) short bf16x8;

#define GLOAD_LDS16(g, l) __builtin_amdgcn_global_load_lds( \
    (const __attribute__((address_space(1))) void*)(g), \
    (__attribute__((address_space(3))) void*)(l), 16, 0, 0)

__device__ __forceinline__ unsigned short f32_to_bf16(float f) {
    union { float f; unsigned int u; } v; v.f = f;
    unsigned int r = v.u + 0x7FFF + ((v.u >> 16) & 1);  // RNE
    return (unsigned short)(r >> 16);
}

// ---------------- setup: counting sort by task + tile table ----------------
__global__ void setup_kernel(const int* __restrict__ task, int* __restrict__ perm,
                             int* __restrict__ offs, int* __restrict__ table) {
    __shared__ int cnt[T_TASKS];
    __shared__ int cur[T_TASKS];
    int tid = threadIdx.x;
    if (tid < T_TASKS) cnt[tid] = 0;
    __syncthreads();
    for (int b = tid; b < B_ROWS; b += blockDim.x)
        atomicAdd(&cnt[task[b]], 1);
    __syncthreads();
    if (tid == 0) {
        int o = 0;
        for (int t = 0; t < T_TASKS; ++t) { offs[t] = o; cur[t] = o; o += cnt[t]; }
        offs[T_TASKS] = o;
        int s = 0;
        for (int t = 0; t < T_TASKS; ++t) {
            int nt = (cnt[t] + BM - 1) / BM;
            for (int j = 0; j < nt; ++j) table[s++] = (t << 16) | j;
        }
        for (; s < MAXTILES; ++s) table[s] = -1;
    }
    __syncthreads();
    for (int b = tid; b < B_ROWS; b += blockDim.x) {
        int t = task[b];
        int pos = atomicAdd(&cur[t], 1);
        perm[pos] = b;
    }
}

// ---------------- permute + cast x -> bf16 ----------------
__global__ void permute_cast_kernel(const float* __restrict__ x, const int* __restrict__ perm,
                                    unsigned short* __restrict__ xp) {
    int rowp = blockIdx.x;
    int src = perm[rowp];
    const float4* xin = reinterpret_cast<const float4*>(x + (size_t)src * 1024);
    unsigned short* dst = xp + (size_t)rowp * 1024;
    int c4 = threadIdx.x;
    float4 v = xin[c4];
    ushort4 o;
    o.x = f32_to_bf16(v.x); o.y = f32_to_bf16(v.y);
    o.z = f32_to_bf16(v.z); o.w = f32_to_bf16(v.w);
    *reinterpret_cast<ushort4*>(dst + c4 * 4) = o;
}

// ---------------- VAE reparameterization ----------------
__global__ void vae_kernel(const float* __restrict__ scat, const float* __restrict__ eps,
                           const int* __restrict__ perm, unsigned short* __restrict__ z) {
    int rowp = blockIdx.x;
    int c = threadIdx.x;
    int src = perm[rowp];
    float mu = scat[(size_t)rowp * 512 + c];
    float ls = scat[(size_t)rowp * 512 + 256 + c];
    float e  = eps[(size_t)src * 256 + c];
    z[(size_t)rowp * 256 + c] = f32_to_bf16(mu + __expf(ls) * e);
}

// ---------------- weight transpose+cast: f32 [K][N] -> bf16 [N][K] ----------------
// grid (K/64, N/64, T), block 256. LDS 64x64 tile, XOR chunk swizzle (4-elem chunks).
__global__ __launch_bounds__(256)
void transpose_cast_kernel(const float* __restrict__ W, unsigned short* __restrict__ Wt,
                           int K, int N) {
    const size_t toff = (size_t)blockIdx.z * K * N;
    const float* Ws = W + toff;
    unsigned short* Wd = Wt + toff;
    const int k0 = blockIdx.x * 64;
    const int n0 = blockIdx.y * 64;
    __shared__ unsigned short Tt[64 * 64];
    const int tid = threadIdx.x;
    const int n = tid & 63;
    const int kq = tid >> 6;        // 0..3 -> k = kq*16 .. +15
    #pragma unroll
    for (int i = 0; i < 4; ++i) {
        int kk = kq * 16 + i * 4;
        const float* p = Ws + (size_t)(k0 + kk) * N + n0 + n;
        float v0 = p[0];
        float v1 = p[(size_t)N];
        float v2 = p[(size_t)2 * N];
        float v3 = p[(size_t)3 * N];
        unsigned int lo = (unsigned int)f32_to_bf16(v0) | ((unsigned int)f32_to_bf16(v1) << 16);
        unsigned int hi = (unsigned int)f32_to_bf16(v2) | ((unsigned int)f32_to_bf16(v3) << 16);
        int c = (kk >> 2) ^ (n & 15);
        *reinterpret_cast<uint2*>(Tt + n * 64 + c * 4) = make_uint2(lo, hi);
    }
    __syncthreads();
    #pragma unroll
    for (int it = 0; it < 2; ++it) {
        int c  = it * 256 + tid;
        int nn = c >> 3;
        int cg = c & 7;
        int c1 = (cg * 2) ^ (nn & 15);
        int c2 = (cg * 2 + 1) ^ (nn & 15);
        uint2 a = *reinterpret_cast<const uint2*>(Tt + nn * 64 + c1 * 4);
        uint2 b = *reinterpret_cast<const uint2*>(Tt + nn * 64 + c2 * 4);
        uint4 o = make_uint4(a.x, a.y, b.x, b.y);
        *reinterpret_cast<uint4*>(Wd + (size_t)(n0 + nn) * K + k0 + cg * 8) = o;
    }
}

// ---------------- fast grouped GEMM (m97 structure) ----------------
// A: bf16 [rowp][K] grouped by task (padded rows). Wt: bf16 [t][N][K]. bias f32 [t][N].
// MODE 0: relu -> bf16 store; MODE 1: f32 store; MODE 2: sigmoid -> f32 scatter via perm
template<int MODE>
__global__ __launch_bounds__(256, 2)
void gemm2_kernel(const unsigned short* __restrict__ A,
                  const unsigned short* __restrict__ Wt,
                  const float* __restrict__ bias, void* __restrict__ dst,
                  const int* __restrict__ offs, const int* __restrict__ table,
                  const int* __restrict__ perm,
                  int K, int N, int ldd, int Btot)
{
    int t, mtile, off, cnt;
    if (table != nullptr) {
        int v = table[blockIdx.x];
        if (v < 0) return;
        t = v >> 16; mtile = v & 0xFFFF;
        off = offs[t]; cnt = offs[t + 1] - off;
    } else {
        t = 0; mtile = blockIdx.x; off = 0; cnt = Btot;
    }
    const int n0 = blockIdx.y * BN;

    __shared__ unsigned short As[BM * BK];
    __shared__ unsigned short Bs[BN * BK];

    const int tid  = threadIdx.x;
    const int lane = tid & 63;
    const int wave = tid >> 6;
    const int wr = wave >> 1, wc = wave & 1;

    // per-lane source base: row (lane>>2), 16B chunk (lane&3) of a 64B (32-elem) k-segment
    const unsigned short* Ab = A + ((size_t)(off + mtile * BM) + (lane >> 2)) * K + (lane & 3) * 8;
    const unsigned short* Bb = Wt + ((size_t)t * N + n0 + (lane >> 2)) * K + (lane & 3) * 8;

    f32x4 acc[4][4];
    #pragma unroll
    for (int m = 0; m < 4; ++m)
        #pragma unroll
        for (int n = 0; n < 4; ++n)
            acc[m][n] = (f32x4){0.f, 0.f, 0.f, 0.f};

    for (int k0 = 0; k0 < K; k0 += BK) {
        #pragma unroll
        for (int jj = 0; jj < 2; ++jj) {
            int j = wave * 2 + jj;                       // 0..7: 16-row slab
            GLOAD_LDS16(Ab + (size_t)j * 16 * K + k0, As + j * 512);
            GLOAD_LDS16(Bb + (size_t)j * 16 * K + k0, Bs + j * 512);
        }
        __syncthreads();

        bf16x8 af[4], bfr[4];
        #pragma unroll
        for (int m = 0; m < 4; ++m)
            af[m] = *reinterpret_cast<const bf16x8*>(
                As + (wr * 64 + m * 16 + (lane & 15)) * BK + (lane >> 4) * 8);
        #pragma unroll
        for (int n = 0; n < 4; ++n)
            bfr[n] = *reinterpret_cast<const bf16x8*>(
                Bs + (wc * 64 + n * 16 + (lane & 15)) * BK + (lane >> 4) * 8);

        #pragma unroll
        for (int m = 0; m < 4; ++m)
            #pragma unroll
            for (int n = 0; n < 4; ++n)
                acc[m][n] = __builtin_amdgcn_mfma_f32_16x16x32_bf16(af[m], bfr[n], acc[m][n], 0, 0, 0);
        __syncthreads();
    }

    const float* bt = bias + (size_t)t * N;
    #pragma unroll
    for (int n = 0; n < 4; ++n) {
        int col = n0 + wc * 64 + n * 16 + (lane & 15);
        float bv = bt[col];
        #pragma unroll
        for (int m = 0; m < 4; ++m) {
            int rbase = mtile * BM + wr * 64 + m * 16 + ((lane >> 4) << 2);
            #pragma unroll
            for (int j = 0; j < 4; ++j) {
                int local = rbase + j;
                if (local >= cnt) continue;
                float v = acc[m][n][j] + bv;
                if (MODE == 0) {
                    ((unsigned short*)dst)[(size_t)(off + local) * ldd + col] =
                        f32_to_bf16(fmaxf(v, 0.f));
                } else if (MODE == 1) {
                    ((float*)dst)[(size_t)(off + local) * ldd + col] = v;
                } else {
                    int grow = perm[off + local];
                    ((float*)dst)[(size_t)grow * ldd + col] = 1.f / (1.f + __expf(-v));
                }
            }
        }
    }
}

// ---------------- round-1 fallback GEMM (f32 weights, in-loop cvt) ----------------
template<int MODE>
__global__ __launch_bounds__(256, 2)
void gemm_kernel(const unsigned short* __restrict__ A, const float* __restrict__ W,
                 const float* __restrict__ bias, void* __restrict__ dst,
                 const int* __restrict__ offs, const int* __restrict__ table,
                 const int* __restrict__ perm,
                 int K, int N, int ldd, int Btot)
{
    int t, mtile, off, cnt;
    if (table != nullptr) {
        int v = table[blockIdx.x];
        if (v < 0) return;
        t = v >> 16; mtile = v & 0xFFFF;
        off = offs[t]; cnt = offs[t + 1] - off;
    } else {
        t = 0; mtile = blockIdx.x; off = 0; cnt = Btot;
    }
    const int n0 = blockIdx.y * BN;
    const float* Wt = W + (size_t)t * K * N;

    __shared__ unsigned short As[BM][LDSS];
    __shared__ unsigned short Bs[BN][LDSS];

    const int tid  = threadIdx.x;
    const int lane = tid & 63;
    const int wave = tid >> 6;
    const int wr = wave >> 1, wc = wave & 1;

    f32x4 acc[4][4];
    #pragma unroll
    for (int m = 0; m < 4; ++m)
        #pragma unroll
        for (int n = 0; n < 4; ++n)
            acc[m][n] = (f32x4){0.f, 0.f, 0.f, 0.f};

    for (int k0 = 0; k0 < K; k0 += BK) {
        #pragma unroll
        for (int it = 0; it < 2; ++it) {
            int c  = it * 256 + tid;
            int mm = c >> 2;
            int kk = (c & 3) << 3;
            int local = mtile * BM + mm;
            uint4 v = make_uint4(0u, 0u, 0u, 0u);
            if (local < cnt)
                v = *reinterpret_cast<const uint4*>(A + (size_t)(off + local) * K + k0 + kk);
            *reinterpret_cast<uint4*>(&As[mm][kk]) = v;
        }
        #pragma unroll
        for (int it = 0; it < 8; ++it) {
            int c  = it * 256 + tid;
            int kk = c >> 6;
            int nn = (c & 63) << 1;
            const float2 v = *reinterpret_cast<const float2*>(
                Wt + (size_t)(k0 + kk) * N + n0 + nn);
            Bs[nn][kk]     = f32_to_bf16(v.x);
            Bs[nn + 1][kk] = f32_to_bf16(v.y);
        }
        __syncthreads();

        bf16x8 af[4], bfr[4];
        #pragma unroll
        for (int m = 0; m < 4; ++m)
            af[m] = *reinterpret_cast<const bf16x8*>(
                &As[wr * 64 + m * 16 + (lane & 15)][(lane >> 4) * 8]);
        #pragma unroll
        for (int n = 0; n < 4; ++n)
            bfr[n] = *reinterpret_cast<const bf16x8*>(
                &Bs[wc * 64 + n * 16 + (lane & 15)][(lane >> 4) * 8]);

        #pragma unroll
        for (int m = 0; m < 4; ++m)
            #pragma unroll
            for (int n = 0; n < 4; ++n)
                acc[m][n] = __builtin_amdgcn_mfma_f32_16x16x32_bf16(af[m], bfr[n], acc[m][n], 0, 0, 0);
        __syncthreads();
    }

    const float* bt = bias + (size_t)t * N;
    #pragma unroll
    for (int n = 0; n < 4; ++n) {
        int col = n0 + wc * 64 + n * 16 + (lane & 15);
        float bv = bt[col];
        #pragma unroll
        for (int m = 0; m < 4; ++m) {
            int rbase = mtile * BM + wr * 64 + m * 16 + ((lane >> 4) << 2);
            #pragma unroll
            for (int j = 0; j < 4; ++j) {
                int local = rbase + j;
                if (local >= cnt) continue;
                float v = acc[m][n][j] + bv;
                if (MODE == 0) {
                    ((unsigned short*)dst)[(size_t)(off + local) * ldd + col] =
                        f32_to_bf16(fmaxf(v, 0.f));
                } else if (MODE == 1) {
                    ((float*)dst)[(size_t)(off + local) * ldd + col] = v;
                } else {
                    int grow = perm[off + local];
                    ((float*)dst)[(size_t)grow * ldd + col] = 1.f / (1.f + __expf(-v));
                }
            }
        }
    }
}

extern "C" void kernel_launch(void* const* d_in, const int* in_sizes, int n_in,
                              void* d_out, int out_size, void* d_ws, size_t ws_size,
                              hipStream_t stream) {
    const float* x      = (const float*)d_in[0];
    const int*   task   = (const int*)d_in[1];
    const float* eps    = (const float*)d_in[2];
    const float* enc_W1 = (const float*)d_in[3];
    const float* enc_b1 = (const float*)d_in[4];
    const float* enc_W2 = (const float*)d_in[5];
    const float* enc_b2 = (const float*)d_in[6];
    const float* enc_W3 = (const float*)d_in[7];
    const float* enc_b3 = (const float*)d_in[8];
    const float* enc_W4 = (const float*)d_in[9];
    const float* enc_b4 = (const float*)d_in[10];
    const float* ds_W1  = (const float*)d_in[11];
    const float* ds_b1  = (const float*)d_in[12];
    const float* ds_W2  = (const float*)d_in[13];
    const float* ds_b2  = (const float*)d_in[14];
    const float* hd_W1  = (const float*)d_in[15];
    const float* hd_b1  = (const float*)d_in[16];
    const float* hd_W2  = (const float*)d_in[17];
    const float* hd_b2  = (const float*)d_in[18];
    float* out = (float*)d_out;

    // ---- fast-path workspace layout ----
    char* ws = (char*)d_ws;
    int* perm  = (int*)ws;
    int* offs  = (int*)(ws + 16384);
    int* table = (int*)(ws + 16384 + 256);
    char* p = ws + 32768;
    unsigned short* xp = (unsigned short*)p; p += (size_t)PADROWS * 1024 * 2;
    unsigned short* h1 = (unsigned short*)p; p += (size_t)PADROWS * 2048 * 2;
    unsigned short* h2 = (unsigned short*)p; p += (size_t)PADROWS * 2048 * 2;
    unsigned short* zb = (unsigned short*)p; p += (size_t)PADROWS * 256 * 2;
    unsigned short* tw1  = (unsigned short*)p; p += (size_t)8 * 2048 * 1024 * 2;
    unsigned short* tw2  = (unsigned short*)p; p += (size_t)8 * 2048 * 2048 * 2;
    unsigned short* tw3  = (unsigned short*)p; p += (size_t)8 * 2048 * 2048 * 2;
    unsigned short* tw4  = (unsigned short*)p; p += (size_t)8 * 512 * 2048 * 2;
    unsigned short* tds1 = (unsigned short*)p; p += (size_t)2048 * 256 * 2;
    unsigned short* tds2 = (unsigned short*)p; p += (size_t)2048 * 2048 * 2;
    unsigned short* thd1 = (unsigned short*)p; p += (size_t)8 * 2048 * 2048 * 2;
    unsigned short* thd2 = (unsigned short*)p; p += (size_t)8 * 1024 * 2048 * 2;
    size_t need = (size_t)(p - ws);
    float* scat = out;   // reuse d_out as 8 MB scat scratch; fully overwritten later

    setup_kernel<<<1, 1024, 0, stream>>>(task, perm, offs, table);
    permute_cast_kernel<<<B_ROWS, 256, 0, stream>>>(x, perm, xp);

    if (ws_size >= need) {
        // ---- pre-transpose + cast all weights to bf16 [N][K] ----
        transpose_cast_kernel<<<dim3(1024/64, 2048/64, 8), 256, 0, stream>>>(enc_W1, tw1, 1024, 2048);
        transpose_cast_kernel<<<dim3(2048/64, 2048/64, 8), 256, 0, stream>>>(enc_W2, tw2, 2048, 2048);
        transpose_cast_kernel<<<dim3(2048/64, 2048/64, 8), 256, 0, stream>>>(enc_W3, tw3, 2048, 2048);
        transpose_cast_kernel<<<dim3(2048/64,  512/64, 8), 256, 0, stream>>>(enc_W4, tw4, 2048, 512);
        transpose_cast_kernel<<<dim3( 256/64, 2048/64, 1), 256, 0, stream>>>(ds_W1, tds1, 256, 2048);
        transpose_cast_kernel<<<dim3(2048/64, 2048/64, 1), 256, 0, stream>>>(ds_W2, tds2, 2048, 2048);
        transpose_cast_kernel<<<dim3(2048/64, 2048/64, 8), 256, 0, stream>>>(hd_W1, thd1, 2048, 2048);
        transpose_cast_kernel<<<dim3(2048/64, 1024/64, 8), 256, 0, stream>>>(hd_W2, thd2, 2048, 1024);

        gemm2_kernel<0><<<dim3(MAXTILES, 16), 256, 0, stream>>>(xp, tw1, enc_b1, h1, offs, table, nullptr, 1024, 2048, 2048, B_ROWS);
        gemm2_kernel<0><<<dim3(MAXTILES, 16), 256, 0, stream>>>(h1, tw2, enc_b2, h2, offs, table, nullptr, 2048, 2048, 2048, B_ROWS);
        gemm2_kernel<0><<<dim3(MAXTILES, 16), 256, 0, stream>>>(h2, tw3, enc_b3, h1, offs, table, nullptr, 2048, 2048, 2048, B_ROWS);
        gemm2_kernel<1><<<dim3(MAXTILES, 4), 256, 0, stream>>>(h1, tw4, enc_b4, scat, offs, table, nullptr, 2048, 512, 512, B_ROWS);

        vae_kernel<<<B_ROWS, 256, 0, stream>>>(scat, eps, perm, zb);

        gemm2_kernel<0><<<dim3(32, 16), 256, 0, stream>>>(zb, tds1, ds_b1, h2, nullptr, nullptr, nullptr, 256, 2048, 2048, B_ROWS);
        gemm2_kernel<0><<<dim3(32, 16), 256, 0, stream>>>(h2, tds2, ds_b2, h1, nullptr, nullptr, nullptr, 2048, 2048, 2048, B_ROWS);

        gemm2_kernel<0><<<dim3(MAXTILES, 16), 256, 0, stream>>>(h1, thd1, hd_b1, h2, offs, table, nullptr, 2048, 2048, 2048, B_ROWS);
        gemm2_kernel<2><<<dim3(MAXTILES, 8), 256, 0, stream>>>(h2, thd2, hd_b2, out, offs, table, perm, 2048, 1024, 1024, B_ROWS);
    } else {
        // ---- round-1 fallback (f32 weights, in-loop cvt) ----
        gemm_kernel<0><<<dim3(MAXTILES, 16), 256, 0, stream>>>(xp, enc_W1, enc_b1, h1, offs, table, nullptr, 1024, 2048, 2048, B_ROWS);
        gemm_kernel<0><<<dim3(MAXTILES, 16), 256, 0, stream>>>(h1, enc_W2, enc_b2, h2, offs, table, nullptr, 2048, 2048, 2048, B_ROWS);
        gemm_kernel<0><<<dim3(MAXTILES, 16), 256, 0, stream>>>(h2, enc_W3, enc_b3, h1, offs, table, nullptr, 2048, 2048, 2048, B_ROWS);
        gemm_kernel<1><<<dim3(MAXTILES, 4), 256, 0, stream>>>(h1, enc_W4, enc_b4, scat, offs, table, nullptr, 2048, 512, 512, B_ROWS);

        vae_kernel<<<B_ROWS, 256, 0, stream>>>(scat, eps, perm, zb);

        gemm_kernel<0><<<dim3(32, 16), 256, 0, stream>>>(zb, ds_W1, ds_b1, h2, nullptr, nullptr, nullptr, 256, 2048, 2048, B_ROWS);
        gemm_kernel<0><<<dim3(32, 16), 256, 0, stream>>>(h2, ds_W2, ds_b2, h1, nullptr, nullptr, nullptr, 2048, 2048, 2048, B_ROWS);

        gemm_kernel<0><<<dim3(MAXTILES, 16), 256, 0, stream>>>(h1, hd_W1, hd_b1, h2, offs, table, nullptr, 2048, 2048, 2048, B_ROWS);
        gemm_kernel<2><<<dim3(MAXTILES, 8), 256, 0, stream>>>(h2, hd_W2, hd_b2, out, offs, table, perm, 2048, 1024, 1024, B_ROWS);
    }
}